// Round 1
// baseline (540.493 us; speedup 1.0000x reference)
//
#include <hip/hip_runtime.h>
#include <cstdint>
#include <cstddef>

// Problem constants
constexpr int B_   = 64;
constexpr int CIN  = 96;
constexpr int H_   = 28;
constexpr int W_   = 28;
constexpr int P_   = 784;      // H*W
constexpr int CMID = 576;
constexpr int COUT = 96;
constexpr int NOUT = B_ * COUT * P_;  // 4816896
constexpr float NBITF = 127.0f;
constexpr float EPSF  = 1e-5f;

// GEMM tiling
constexpr int PT = 112;  // pixel tile (784 = 7*112)
constexpr int KC = 48;   // K chunk

// ---------------------------------------------------------------------------
// Weight prep: fold BN, per-output-channel symmetric quant.
// blocks 0..575   -> conv1 oc (K=96)  -> w1q fp32, bf1
// blocks 576..1151-> conv2 oc (K=9)   -> w2qi int8, ws2, bf2
// blocks 1152..1247-> conv3 oc (K=576)-> w3q fp32, bf3
// ---------------------------------------------------------------------------
__global__ __launch_bounds__(64)
void prep_weights(const float* __restrict__ w1, const float* __restrict__ g1,
                  const float* __restrict__ b1, const float* __restrict__ m1,
                  const float* __restrict__ v1,
                  const float* __restrict__ w2, const float* __restrict__ g2,
                  const float* __restrict__ b2, const float* __restrict__ m2,
                  const float* __restrict__ v2,
                  const float* __restrict__ w3, const float* __restrict__ g3,
                  const float* __restrict__ b3, const float* __restrict__ m3,
                  const float* __restrict__ v3,
                  float* __restrict__ w1q, float* __restrict__ bf1,
                  int8_t* __restrict__ w2qi, float* __restrict__ ws2,
                  float* __restrict__ bf2,
                  float* __restrict__ w3q, float* __restrict__ bf3)
{
    int blk  = blockIdx.x;
    int lane = threadIdx.x;  // 64 threads = 1 wave

    const float *w, *g, *bb, *mm, *vv;
    int oc, K, which;
    if (blk < CMID)            { which = 0; w = w1; g = g1; bb = b1; mm = m1; vv = v1; oc = blk;            K = CIN;  }
    else if (blk < 2 * CMID)   { which = 1; w = w2; g = g2; bb = b2; mm = m2; vv = v2; oc = blk - CMID;     K = 9;    }
    else                       { which = 2; w = w3; g = g3; bb = b3; mm = m3; vv = v3; oc = blk - 2 * CMID; K = CMID; }

    float scale = g[oc] / sqrtf(vv[oc] + EPSF);

    float mx = 0.f;
    for (int k = lane; k < K; k += 64)
        mx = fmaxf(mx, fabsf(w[oc * K + k] * scale));
    #pragma unroll
    for (int off = 1; off < 64; off <<= 1)
        mx = fmaxf(mx, __shfl_xor(mx, off));

    float s = mx / NBITF;

    for (int k = lane; k < K; k += 64) {
        float wf = w[oc * K + k] * scale;
        float q  = rintf(wf / s);
        q = fminf(fmaxf(q, -127.f), 127.f);
        if (which == 0)      w1q[oc * K + k] = q * s;
        else if (which == 1) w2qi[oc * 9 + k] = (int8_t)q;
        else                 w3q[oc * K + k] = q * s;
    }
    if (lane == 0) {
        float bf = bb[oc] - mm[oc] * scale;
        if (which == 0)      bf1[oc] = bf;
        else if (which == 1) { bf2[oc] = bf; ws2[oc] = s; }
        else                 bf3[oc] = bf;
    }
}

// ---------------------------------------------------------------------------
// conv1: 1x1 expansion (96->576), input quant fused, ReLU6, output quant to i8
// grid (42, 64): blockIdx.x -> octile = x%6 (96 oc each), ptile = x/6 (112 px)
// block 256: px = tid&15, oy = tid>>4; each thread: 6 oc x 7 px
// ---------------------------------------------------------------------------
__global__ __launch_bounds__(256)
void conv1_kernel(const float* __restrict__ x, const float* __restrict__ w1q,
                  const float* __restrict__ bf1, const float* __restrict__ r0,
                  const float* __restrict__ r1, const int* __restrict__ cluster,
                  int8_t* __restrict__ y1q)
{
    __shared__ float xs[KC][PT];        // 21504 B
    __shared__ float wsh[96][KC + 1];   // 18816 B (pad -> stride 49, no conflicts)

    int b      = blockIdx.y;
    int octile = blockIdx.x % 6;
    int ptile  = blockIdx.x / 6;
    int oc0    = octile * 96;
    int p0     = ptile * PT;
    int tid    = threadIdx.x;
    int px     = tid & 15;
    int oy     = tid >> 4;

    int   c  = cluster[0];
    float s0 = r0[c] / NBITF;
    float s1 = r1[c] / NBITF;

    float acc[6][7];
    #pragma unroll
    for (int i = 0; i < 6; i++)
        #pragma unroll
        for (int j = 0; j < 7; j++) acc[i][j] = 0.f;

    for (int k0 = 0; k0 < CIN; k0 += KC) {
        // stage x chunk, quantize->dequantize (exact fake-quant values)
        for (int idx = tid; idx < KC * PT; idx += 256) {
            int ic = idx / PT, p = idx % PT;
            float v = x[(b * CIN + k0 + ic) * P_ + p0 + p];
            float q = rintf(v / s0);
            q = fminf(fmaxf(q, -127.f), 127.f);
            xs[ic][p] = q * s0;
        }
        // stage w chunk
        for (int idx = tid; idx < 96 * KC; idx += 256) {
            int o = idx / KC, kk = idx % KC;
            wsh[o][kk] = w1q[(oc0 + o) * CIN + k0 + kk];
        }
        __syncthreads();

        #pragma unroll 4
        for (int ic = 0; ic < KC; ic++) {
            float xv[7], wv[6];
            #pragma unroll
            for (int j = 0; j < 7; j++) xv[j] = xs[ic][px + 16 * j];
            #pragma unroll
            for (int i = 0; i < 6; i++) wv[i] = wsh[oy + 16 * i][ic];
            #pragma unroll
            for (int i = 0; i < 6; i++)
                #pragma unroll
                for (int j = 0; j < 7; j++)
                    acc[i][j] = fmaf(wv[i], xv[j], acc[i][j]);
        }
        __syncthreads();
    }

    #pragma unroll
    for (int i = 0; i < 6; i++) {
        int   oc   = oc0 + oy + 16 * i;
        float bias = bf1[oc];
        #pragma unroll
        for (int j = 0; j < 7; j++) {
            float v = acc[i][j] + bias;
            v = fminf(fmaxf(v, 0.f), 6.f);           // ReLU6
            float q = fminf(rintf(v / s1), 127.f);   // v>=0 so only upper clip
            y1q[(b * CMID + oc) * P_ + p0 + px + 16 * j] = (int8_t)q;
        }
    }
}

// ---------------------------------------------------------------------------
// conv2: 3x3 depthwise, pad 1, exact integer accumulation, ReLU6, quant to i8
// one thread per output element
// ---------------------------------------------------------------------------
__global__ __launch_bounds__(256)
void conv2_kernel(const int8_t* __restrict__ y1q, const int8_t* __restrict__ w2qi,
                  const float* __restrict__ ws2, const float* __restrict__ bf2,
                  const float* __restrict__ r1, const float* __restrict__ r2,
                  const int* __restrict__ cluster,
                  int8_t* __restrict__ y2q)
{
    int gid = blockIdx.x * 256 + threadIdx.x;
    if (gid >= B_ * CMID * P_) return;

    int p  = gid % P_;
    int bc = gid / P_;
    int ch = bc % CMID;
    int y0 = p / W_, x0 = p % W_;

    int   c  = cluster[0];
    float s1 = r1[c] / NBITF;
    float s2 = r2[c] / NBITF;

    const int8_t* in = y1q + (long)bc * P_;
    int acc = 0;
    #pragma unroll
    for (int dy = -1; dy <= 1; dy++) {
        int yy = y0 + dy;
        if ((unsigned)yy >= (unsigned)H_) continue;
        #pragma unroll
        for (int dx = -1; dx <= 1; dx++) {
            int xx = x0 + dx;
            if ((unsigned)xx >= (unsigned)W_) continue;
            acc += (int)in[yy * W_ + xx] * (int)w2qi[ch * 9 + (dy + 1) * 3 + (dx + 1)];
        }
    }
    float v = (float)acc * (s1 * ws2[ch]) + bf2[ch];
    v = fminf(fmaxf(v, 0.f), 6.f);
    float q = fminf(rintf(v / s2), 127.f);
    y2q[gid] = (int8_t)q;
}

// ---------------------------------------------------------------------------
// conv3: 1x1 projection (576->96) + residual + final quant; writes out and s3
// grid (7, 64); block 256; 6 oc x 7 px per thread; K=576 in chunks of 48
// ---------------------------------------------------------------------------
__global__ __launch_bounds__(256)
void conv3_kernel(const int8_t* __restrict__ y2q, const float* __restrict__ w3q,
                  const float* __restrict__ bf3, const float* __restrict__ x,
                  const float* __restrict__ r2, const float* __restrict__ r3,
                  const int* __restrict__ cluster,
                  float* __restrict__ out)
{
    __shared__ float xs[KC][PT];
    __shared__ float wsh[96][KC + 1];

    int b   = blockIdx.y;
    int p0  = blockIdx.x * PT;
    int tid = threadIdx.x;
    int px  = tid & 15;
    int oy  = tid >> 4;

    int   c  = cluster[0];
    float s2 = r2[c] / NBITF;
    float s3 = r3[c] / NBITF;

    float acc[6][7];
    #pragma unroll
    for (int i = 0; i < 6; i++)
        #pragma unroll
        for (int j = 0; j < 7; j++) acc[i][j] = 0.f;

    for (int k0 = 0; k0 < CMID; k0 += KC) {
        for (int idx = tid; idx < KC * PT; idx += 256) {
            int ic = idx / PT, p = idx % PT;
            xs[ic][p] = (float)y2q[(b * CMID + k0 + ic) * P_ + p0 + p] * s2;
        }
        for (int idx = tid; idx < 96 * KC; idx += 256) {
            int o = idx / KC, kk = idx % KC;
            wsh[o][kk] = w3q[o * CMID + k0 + kk];
        }
        __syncthreads();

        #pragma unroll 4
        for (int ic = 0; ic < KC; ic++) {
            float xv[7], wv[6];
            #pragma unroll
            for (int j = 0; j < 7; j++) xv[j] = xs[ic][px + 16 * j];
            #pragma unroll
            for (int i = 0; i < 6; i++) wv[i] = wsh[oy + 16 * i][ic];
            #pragma unroll
            for (int i = 0; i < 6; i++)
                #pragma unroll
                for (int j = 0; j < 7; j++)
                    acc[i][j] = fmaf(wv[i], xv[j], acc[i][j]);
        }
        __syncthreads();
    }

    #pragma unroll
    for (int i = 0; i < 6; i++) {
        int   oc   = oy + 16 * i;
        float bias = bf3[oc];
        #pragma unroll
        for (int j = 0; j < 7; j++) {
            int   gi = (b * COUT + oc) * P_ + p0 + px + 16 * j;
            float v  = acc[i][j] + bias + x[gi];  // residual
            float q  = fminf(fmaxf(rintf(v / s3), -127.f), 127.f) * s3;
            out[gi] = q;
        }
    }
    if (blockIdx.x == 0 && blockIdx.y == 0 && tid == 0)
        out[NOUT] = s3;  // second tuple output: the scale
}

// ---------------------------------------------------------------------------
extern "C" void kernel_launch(void* const* d_in, const int* in_sizes, int n_in,
                              void* d_out, int out_size, void* d_ws, size_t ws_size,
                              hipStream_t stream)
{
    const float* x  = (const float*)d_in[0];
    const float* w1 = (const float*)d_in[1];
    const float* g1 = (const float*)d_in[2];
    const float* b1 = (const float*)d_in[3];
    const float* m1 = (const float*)d_in[4];
    const float* v1 = (const float*)d_in[5];
    const float* w2 = (const float*)d_in[6];
    const float* g2 = (const float*)d_in[7];
    const float* b2 = (const float*)d_in[8];
    const float* m2 = (const float*)d_in[9];
    const float* v2 = (const float*)d_in[10];
    const float* w3 = (const float*)d_in[11];
    const float* g3 = (const float*)d_in[12];
    const float* b3 = (const float*)d_in[13];
    const float* m3 = (const float*)d_in[14];
    const float* v3 = (const float*)d_in[15];
    const float* r0 = (const float*)d_in[16];
    const float* r1 = (const float*)d_in[17];
    const float* r2 = (const float*)d_in[18];
    const float* r3 = (const float*)d_in[19];
    const int*   cl = (const int*)d_in[20];

    float* out = (float*)d_out;

    // workspace carve-up (256B aligned)
    char*  ws  = (char*)d_ws;
    size_t off = 0;
    auto carve = [&](size_t bytes) {
        size_t cur = off;
        off = (off + bytes + 255) & ~(size_t)255;
        return (void*)(ws + cur);
    };
    float*  w1q  = (float*)carve((size_t)CMID * CIN * 4);   // 221184
    float*  w3q  = (float*)carve((size_t)COUT * CMID * 4);  // 221184
    float*  bf1  = (float*)carve(CMID * 4);
    float*  bf3  = (float*)carve(COUT * 4);
    int8_t* w2qi = (int8_t*)carve(CMID * 9);
    float*  ws2  = (float*)carve(CMID * 4);
    float*  bf2  = (float*)carve(CMID * 4);
    int8_t* y1q  = (int8_t*)carve((size_t)B_ * CMID * P_);  // 28.9 MB
    int8_t* y2q  = (int8_t*)carve((size_t)B_ * CMID * P_);  // 28.9 MB
    (void)ws_size; (void)in_sizes; (void)n_in; (void)out_size;

    prep_weights<<<dim3(2 * CMID + COUT), dim3(64), 0, stream>>>(
        w1, g1, b1, m1, v1, w2, g2, b2, m2, v2, w3, g3, b3, m3, v3,
        w1q, bf1, w2qi, ws2, bf2, w3q, bf3);

    conv1_kernel<<<dim3(42, B_), dim3(256), 0, stream>>>(
        x, w1q, bf1, r0, r1, cl, y1q);

    conv2_kernel<<<dim3((B_ * CMID * P_) / 256), dim3(256), 0, stream>>>(
        y1q, w2qi, ws2, bf2, r1, r2, cl, y2q);

    conv3_kernel<<<dim3(7, B_), dim3(256), 0, stream>>>(
        y2q, w3q, bf3, x, r2, r3, cl, out);
}

// Round 2
// 210.207 us; speedup vs baseline: 2.5712x; 2.5712x over previous
//
#include <hip/hip_runtime.h>
#include <cstdint>
#include <cstddef>

typedef int  v4i  __attribute__((ext_vector_type(4)));
typedef unsigned int uint_t;

constexpr int B_   = 64;
constexpr int CIN  = 96;
constexpr int P_   = 784;      // 28*28
constexpr int CMID = 576;
constexpr int COUT = 96;
constexpr int NOUT = B_ * COUT * P_;  // 4816896
constexpr float NBITF = 127.0f;
constexpr float EPSF  = 1e-5f;

__device__ __forceinline__ int sx(uint_t v, int i) {
    return (int)(signed char)(v >> (8 * i));
}

// ---------------------------------------------------------------------------
// Weight prep: fold BN, per-oc symmetric quant -> int8 levels + scales.
// blocks 0..575    -> conv1 oc (K=96)
// blocks 576..1151 -> conv2 oc (K=9, stored stride 12 for aligned dword loads)
// blocks 1152..1247-> conv3 oc (K=576)
// ---------------------------------------------------------------------------
__global__ __launch_bounds__(64)
void prep_weights(const float* __restrict__ w1, const float* __restrict__ g1,
                  const float* __restrict__ b1, const float* __restrict__ m1,
                  const float* __restrict__ v1,
                  const float* __restrict__ w2, const float* __restrict__ g2,
                  const float* __restrict__ b2, const float* __restrict__ m2,
                  const float* __restrict__ v2,
                  const float* __restrict__ w3, const float* __restrict__ g3,
                  const float* __restrict__ b3, const float* __restrict__ m3,
                  const float* __restrict__ v3,
                  int8_t* __restrict__ w1qi, float* __restrict__ ws1, float* __restrict__ bf1,
                  int8_t* __restrict__ w2qi, float* __restrict__ ws2, float* __restrict__ bf2,
                  int8_t* __restrict__ w3qi, float* __restrict__ ws3, float* __restrict__ bf3)
{
    int blk  = blockIdx.x;
    int lane = threadIdx.x;

    const float *w, *g, *bb, *mm, *vv;
    int oc, K, which;
    if (blk < CMID)            { which = 0; w = w1; g = g1; bb = b1; mm = m1; vv = v1; oc = blk;            K = CIN;  }
    else if (blk < 2 * CMID)   { which = 1; w = w2; g = g2; bb = b2; mm = m2; vv = v2; oc = blk - CMID;     K = 9;    }
    else                       { which = 2; w = w3; g = g3; bb = b3; mm = m3; vv = v3; oc = blk - 2 * CMID; K = CMID; }

    float scale = g[oc] / sqrtf(vv[oc] + EPSF);

    float mx = 0.f;
    for (int k = lane; k < K; k += 64)
        mx = fmaxf(mx, fabsf(w[oc * K + k] * scale));
    #pragma unroll
    for (int off = 1; off < 64; off <<= 1)
        mx = fmaxf(mx, __shfl_xor(mx, off));

    float s = mx / NBITF;

    for (int k = lane; k < K; k += 64) {
        float wf = w[oc * K + k] * scale;
        float q  = fminf(fmaxf(rintf(wf / s), -127.f), 127.f);
        if (which == 0)      w1qi[oc * 96 + k]  = (int8_t)q;
        else if (which == 1) w2qi[oc * 12 + k]  = (int8_t)q;
        else                 w3qi[oc * 576 + k] = (int8_t)q;
    }
    if (lane == 0) {
        float bf = bb[oc] - mm[oc] * scale;
        if (which == 0)      { ws1[oc] = s; bf1[oc] = bf; }
        else if (which == 1) { ws2[oc] = s; bf2[oc] = bf; }
        else                 { ws3[oc] = s; bf3[oc] = bf; }
    }
}

// ---------------------------------------------------------------------------
// conv1: 1x1 expansion 96->576 via int8 MFMA 16x16x64 (K padded 96->128).
// Block 256 = 4 waves; tile 192 oc x 112 px; wave w: 3 m-subtiles (48 oc), 7 n.
// Grid (3*7, 64).
// ---------------------------------------------------------------------------
__global__ __launch_bounds__(256)
void conv1_kernel(const float* __restrict__ x, const int8_t* __restrict__ w1qi,
                  const float* __restrict__ ws1, const float* __restrict__ bf1,
                  const float* __restrict__ r0, const float* __restrict__ r1,
                  const int* __restrict__ cluster, int8_t* __restrict__ y1q)
{
    __shared__ int Bsh[112 * 36];   // [px][144 B]: K=128 + 16 B pad
    __shared__ int Ash[192 * 36];   // [oc][144 B]

    int tid = threadIdx.x;
    int b   = blockIdx.y;
    int mt  = blockIdx.x / 7;
    int nt  = blockIdx.x - mt * 7;
    int oc0 = mt * 192;
    int p0  = nt * 112;

    int   c      = cluster[0];
    float r0c    = r0[c];
    float s0     = r0c / NBITF;
    float inv_s0 = NBITF / r0c;
    float inv_s1 = NBITF / r1[c];

    // stage X: quantize fp32 -> int8 level, transposed to [p][k]
    char* Bb = (char*)Bsh;
    for (int idx = tid; idx < 96 * 112; idx += 256) {
        int ic = idx / 112, p = idx - ic * 112;
        float v = x[(b * CIN + ic) * P_ + p0 + p];
        float q = fminf(fmaxf(rintf(v * inv_s0), -127.f), 127.f);
        Bb[p * 144 + ic] = (char)(int)q;
    }
    for (int idx = tid; idx < 112 * 8; idx += 256) {          // zero pad k 96..127
        int p = idx >> 3, d = idx & 7;
        Bsh[p * 36 + 24 + d] = 0;
    }
    const int* w4 = (const int*)w1qi;                          // 24 dwords / oc
    for (int idx = tid; idx < 192 * 24; idx += 256) {
        int m = idx / 24, kd = idx - m * 24;
        Ash[m * 36 + kd] = w4[(oc0 + m) * 24 + kd];
    }
    for (int idx = tid; idx < 192 * 8; idx += 256) {
        int m = idx >> 3, d = idx & 7;
        Ash[m * 36 + 24 + d] = 0;
    }
    __syncthreads();

    int lane = tid & 63;
    int wv   = tid >> 6;
    int n    = lane & 15;
    int q4   = lane >> 4;

    v4i acc[3][7];
    #pragma unroll
    for (int i = 0; i < 3; i++)
        #pragma unroll
        for (int j = 0; j < 7; j++) acc[i][j] = (v4i){0, 0, 0, 0};

    v4i* A4 = (v4i*)Ash;   // 9 v4i per row
    v4i* B4 = (v4i*)Bsh;
    #pragma unroll
    for (int ks = 0; ks < 2; ks++) {
        v4i af[3], bfr[7];
        #pragma unroll
        for (int i = 0; i < 3; i++)
            af[i] = A4[(wv * 48 + i * 16 + n) * 9 + ks * 4 + q4];
        #pragma unroll
        for (int j = 0; j < 7; j++)
            bfr[j] = B4[(j * 16 + n) * 9 + ks * 4 + q4];
        #pragma unroll
        for (int i = 0; i < 3; i++)
            #pragma unroll
            for (int j = 0; j < 7; j++)
                acc[i][j] = __builtin_amdgcn_mfma_i32_16x16x64_i8(af[i], bfr[j], acc[i][j], 0, 0, 0);
    }

    // epilogue: scale, +bias, ReLU6, quantize to int8 level
    #pragma unroll
    for (int i = 0; i < 3; i++) {
        #pragma unroll
        for (int r = 0; r < 4; r++) {
            int   oc    = oc0 + wv * 48 + i * 16 + q4 * 4 + r;
            float scale = s0 * ws1[oc];
            float bias  = bf1[oc];
            #pragma unroll
            for (int j = 0; j < 7; j++) {
                int   px = p0 + j * 16 + n;
                float v  = (float)acc[i][j][r] * scale + bias;
                v = fminf(fmaxf(v, 0.f), 6.f);
                int qq = (int)fminf(rintf(v * inv_s1), 127.f);
                y1q[(b * CMID + oc) * P_ + px] = (int8_t)qq;
            }
        }
    }
}

// ---------------------------------------------------------------------------
// conv2: 3x3 depthwise, thread = 4 horizontal px, dword loads, int MAC, ReLU6.
// ---------------------------------------------------------------------------
__global__ __launch_bounds__(256)
void conv2_kernel(const int8_t* __restrict__ y1q, const int8_t* __restrict__ w2qi,
                  const float* __restrict__ ws2, const float* __restrict__ bf2,
                  const float* __restrict__ r1, const float* __restrict__ r2,
                  const int* __restrict__ cluster, int8_t* __restrict__ y2q)
{
    int gid = blockIdx.x * 256 + threadIdx.x;   // < 64*576*196 exactly
    int pd  = gid % 196;
    int bc  = gid / 196;
    int ch  = bc % CMID;
    int y   = pd / 7;
    int x0  = (pd - y * 7) * 4;

    int   c      = cluster[0];
    float s1     = r1[c] / NBITF;
    float inv_s2 = NBITF / r2[c];

    const int* wd = (const int*)(w2qi + ch * 12);
    uint_t wr0 = wd[0], wr1 = wd[1], wr2 = wd[2];
    int wt[9];
    wt[0] = sx(wr0, 0); wt[1] = sx(wr0, 1); wt[2] = sx(wr0, 2);
    wt[3] = sx(wr0, 3); wt[4] = sx(wr1, 0); wt[5] = sx(wr1, 1);
    wt[6] = sx(wr1, 2); wt[7] = sx(wr1, 3); wt[8] = sx(wr2, 0);

    const int8_t* in = y1q + bc * P_;
    int acc0 = 0, acc1 = 0, acc2 = 0, acc3 = 0;
    #pragma unroll
    for (int r = -1; r <= 1; r++) {
        int yy = y + r;
        if ((unsigned)yy >= 28u) continue;
        const int* rowp = (const int*)(in + yy * 28 + x0);
        uint_t cur  = *rowp;
        uint_t prev = (x0 > 0)  ? *(rowp - 1) : 0u;
        uint_t next = (x0 < 24) ? *(rowp + 1) : 0u;
        int bm1 = sx(prev, 3);
        int b0  = sx(cur, 0), b1 = sx(cur, 1), b2 = sx(cur, 2), b3 = sx(cur, 3);
        int b4  = sx(next, 0);
        int w0 = wt[(r + 1) * 3], w1 = wt[(r + 1) * 3 + 1], w2v = wt[(r + 1) * 3 + 2];
        acc0 += w0 * bm1 + w1 * b0 + w2v * b1;
        acc1 += w0 * b0  + w1 * b1 + w2v * b2;
        acc2 += w0 * b1  + w1 * b2 + w2v * b3;
        acc3 += w0 * b2  + w1 * b3 + w2v * b4;
    }

    float sc   = s1 * ws2[ch];
    float bias = bf2[ch];
    uint_t pack = 0;
    int a[4] = {acc0, acc1, acc2, acc3};
    #pragma unroll
    for (int i = 0; i < 4; i++) {
        float v = (float)a[i] * sc + bias;
        v = fminf(fmaxf(v, 0.f), 6.f);
        int qq = (int)fminf(rintf(v * inv_s2), 127.f);
        pack |= ((uint_t)qq & 0xffu) << (8 * i);
    }
    ((uint_t*)y2q)[bc * 196 + pd] = pack;
}

// ---------------------------------------------------------------------------
// conv3: 1x1 projection 576->96 via int8 MFMA 16x16x64 (K=576 = 9 steps),
// fused residual + final requant + s3 write.
// Block 256 = 4 waves; tile 96 oc x 64 px; wave w: n-strip 16, 6 m-subtiles.
// K chunked 192 (3 chunks). Grid (13, 64), last n-tile partially masked.
// ---------------------------------------------------------------------------
__global__ __launch_bounds__(256)
void conv3_kernel(const int8_t* __restrict__ y2q, const int8_t* __restrict__ w3qi,
                  const float* __restrict__ ws3, const float* __restrict__ bf3,
                  const float* __restrict__ x, const float* __restrict__ r2,
                  const float* __restrict__ r3, const int* __restrict__ cluster,
                  float* __restrict__ out)
{
    __shared__ int Ash[96 * 52];   // [oc][208 B]: 192 K + 16 pad
    __shared__ int Bsh[64 * 52];   // [px][208 B]

    int tid = threadIdx.x;
    int b   = blockIdx.y;
    int p0  = blockIdx.x * 64;

    int   c      = cluster[0];
    float s2     = r2[c] / NBITF;
    float s3     = r3[c] / NBITF;
    float inv_s3 = NBITF / r3[c];

    int lane = tid & 63;
    int wv   = tid >> 6;
    int n    = lane & 15;
    int q4   = lane >> 4;

    v4i acc[6];
    #pragma unroll
    for (int i = 0; i < 6; i++) acc[i] = (v4i){0, 0, 0, 0};

    const int* w34 = (const int*)w3qi;   // 144 dwords / oc
    v4i* A4 = (v4i*)Ash;                 // 13 v4i per row
    v4i* B4 = (v4i*)Bsh;

    for (int kc = 0; kc < CMID; kc += 192) {
        // stage A: 96 oc x 48 dwords
        for (int idx = tid; idx < 96 * 48; idx += 256) {
            int m = idx / 48, kd = idx - m * 48;
            Ash[m * 52 + kd] = w34[m * 144 + (kc >> 2) + kd];
        }
        // stage B: transpose [ch][p] -> [p][ch] via v_perm (4x4 byte blocks)
        for (int t = tid; t < 768; t += 256) {
            int g  = t >> 4;            // ch quad 0..47
            int pd = t & 15;            // px dword 0..15
            int pbyte = p0 + 4 * pd;
            if (pbyte > 780) pbyte = 780;   // clamp (masked at store)
            const uint8_t* base = (const uint8_t*)y2q + (b * CMID + kc + 4 * g) * P_ + pbyte;
            uint_t r0v = *(const uint_t*)(base);
            uint_t r1v = *(const uint_t*)(base + P_);
            uint_t r2v = *(const uint_t*)(base + 2 * P_);
            uint_t r3v = *(const uint_t*)(base + 3 * P_);
            uint_t u01 = __builtin_amdgcn_perm(r1v, r0v, 0x05010400u);
            uint_t u23 = __builtin_amdgcn_perm(r3v, r2v, 0x05010400u);
            uint_t v01 = __builtin_amdgcn_perm(r1v, r0v, 0x07030602u);
            uint_t v23 = __builtin_amdgcn_perm(r3v, r2v, 0x07030602u);
            int pl = 4 * pd;
            Bsh[(pl + 0) * 52 + g] = __builtin_amdgcn_perm(u23, u01, 0x05040100u);
            Bsh[(pl + 1) * 52 + g] = __builtin_amdgcn_perm(u23, u01, 0x07060302u);
            Bsh[(pl + 2) * 52 + g] = __builtin_amdgcn_perm(v23, v01, 0x05040100u);
            Bsh[(pl + 3) * 52 + g] = __builtin_amdgcn_perm(v23, v01, 0x07060302u);
        }
        __syncthreads();

        #pragma unroll
        for (int ks = 0; ks < 3; ks++) {
            v4i bfr = B4[(wv * 16 + n) * 13 + ks * 4 + q4];
            #pragma unroll
            for (int i = 0; i < 6; i++) {
                v4i afr = A4[(i * 16 + n) * 13 + ks * 4 + q4];
                acc[i] = __builtin_amdgcn_mfma_i32_16x16x64_i8(afr, bfr, acc[i], 0, 0, 0);
            }
        }
        __syncthreads();
    }

    int  px    = p0 + wv * 16 + n;
    bool valid = px < P_;
    #pragma unroll
    for (int i = 0; i < 6; i++) {
        #pragma unroll
        for (int r = 0; r < 4; r++) {
            if (!valid) continue;
            int   oc = i * 16 + q4 * 4 + r;
            int   gi = (b * COUT + oc) * P_ + px;
            float v  = (float)acc[i][r] * (s2 * ws3[oc]) + bf3[oc] + x[gi];
            float qv = fminf(fmaxf(rintf(v * inv_s3), -127.f), 127.f);
            out[gi] = qv * s3;
        }
    }
    if (blockIdx.x == 0 && blockIdx.y == 0 && tid == 0)
        out[NOUT] = s3;
}

// ---------------------------------------------------------------------------
extern "C" void kernel_launch(void* const* d_in, const int* in_sizes, int n_in,
                              void* d_out, int out_size, void* d_ws, size_t ws_size,
                              hipStream_t stream)
{
    const float* x  = (const float*)d_in[0];
    const float* w1 = (const float*)d_in[1];
    const float* g1 = (const float*)d_in[2];
    const float* b1 = (const float*)d_in[3];
    const float* m1 = (const float*)d_in[4];
    const float* v1 = (const float*)d_in[5];
    const float* w2 = (const float*)d_in[6];
    const float* g2 = (const float*)d_in[7];
    const float* b2 = (const float*)d_in[8];
    const float* m2 = (const float*)d_in[9];
    const float* v2 = (const float*)d_in[10];
    const float* w3 = (const float*)d_in[11];
    const float* g3 = (const float*)d_in[12];
    const float* b3 = (const float*)d_in[13];
    const float* m3 = (const float*)d_in[14];
    const float* v3 = (const float*)d_in[15];
    const float* r0 = (const float*)d_in[16];
    const float* r1 = (const float*)d_in[17];
    const float* r2 = (const float*)d_in[18];
    const float* r3 = (const float*)d_in[19];
    const int*   cl = (const int*)d_in[20];

    float* out = (float*)d_out;

    char*  ws  = (char*)d_ws;
    size_t off = 0;
    auto carve = [&](size_t bytes) {
        size_t cur = off;
        off = (off + bytes + 255) & ~(size_t)255;
        return (void*)(ws + cur);
    };
    int8_t* w1qi = (int8_t*)carve((size_t)CMID * 96);
    float*  ws1  = (float*)carve(CMID * 4);
    float*  bf1  = (float*)carve(CMID * 4);
    int8_t* w2qi = (int8_t*)carve((size_t)CMID * 12);
    float*  ws2  = (float*)carve(CMID * 4);
    float*  bf2  = (float*)carve(CMID * 4);
    int8_t* w3qi = (int8_t*)carve((size_t)COUT * 576);
    float*  ws3  = (float*)carve(COUT * 4);
    float*  bf3  = (float*)carve(COUT * 4);
    int8_t* y1q  = (int8_t*)carve((size_t)B_ * CMID * P_);  // 28.9 MB
    int8_t* y2q  = (int8_t*)carve((size_t)B_ * CMID * P_);  // 28.9 MB
    (void)ws_size; (void)in_sizes; (void)n_in; (void)out_size;

    prep_weights<<<dim3(2 * CMID + COUT), dim3(64), 0, stream>>>(
        w1, g1, b1, m1, v1, w2, g2, b2, m2, v2, w3, g3, b3, m3, v3,
        w1qi, ws1, bf1, w2qi, ws2, bf2, w3qi, ws3, bf3);

    conv1_kernel<<<dim3(21, B_), dim3(256), 0, stream>>>(
        x, w1qi, ws1, bf1, r0, r1, cl, y1q);

    conv2_kernel<<<dim3((B_ * CMID * 196) / 256), dim3(256), 0, stream>>>(
        y1q, w2qi, ws2, bf2, r1, r2, cl, y2q);

    conv3_kernel<<<dim3(13, B_), dim3(256), 0, stream>>>(
        y2q, w3qi, ws3, bf3, x, r2, r3, cl, out);
}

// Round 3
// 192.348 us; speedup vs baseline: 2.8100x; 1.0928x over previous
//
#include <hip/hip_runtime.h>
#include <cstdint>
#include <cstddef>

typedef int   v4i __attribute__((ext_vector_type(4)));
typedef float v4f __attribute__((ext_vector_type(4)));
typedef unsigned int u32;

constexpr int B_   = 64;
constexpr int CIN  = 96;
constexpr int P_   = 784;     // 28*28
constexpr int CMID = 576;
constexpr int COUT = 96;
constexpr int NOUT = B_ * COUT * P_;
constexpr float NBITF = 127.0f;
constexpr float EPSF  = 1e-5f;

// Layouts (all int8 "levels"):
//  x8t  [b][px][144] : ic 0..95 data, 96..127 zero (MFMA K-pad), 128..143 slack
//  w1qp [oc][144]    : k 0..95 data, 96..143 zero
//  w2qi [ch][12]     : 9 taps + 3 slack (aligned dword loads)
//  w3qp [oc][592]    : k 0..575 data, 576..591 slack (never read by MFMA)
//  y2qT [b][px][592] : ch-transposed depthwise output (conv3 B operand)

__device__ __forceinline__ int dot3(u32 win, u32 wpk, int acc) {
#if __has_builtin(__builtin_amdgcn_sdot4)
    return __builtin_amdgcn_sdot4((int)win, (int)wpk, acc, false);
#else
    return acc + (int)(signed char)(win)        * (int)(signed char)(wpk)
               + (int)(signed char)(win >> 8)   * (int)(signed char)(wpk >> 8)
               + (int)(signed char)(win >> 16)  * (int)(signed char)(wpk >> 16);
#endif
}

// ---------------------------------------------------------------------------
// Weight prep: fold BN, per-oc symmetric quant -> int8 levels + scales.
// ---------------------------------------------------------------------------
__global__ __launch_bounds__(64)
void prep_weights(const float* __restrict__ w1, const float* __restrict__ g1,
                  const float* __restrict__ b1, const float* __restrict__ m1,
                  const float* __restrict__ v1,
                  const float* __restrict__ w2, const float* __restrict__ g2,
                  const float* __restrict__ b2, const float* __restrict__ m2,
                  const float* __restrict__ v2,
                  const float* __restrict__ w3, const float* __restrict__ g3,
                  const float* __restrict__ b3, const float* __restrict__ m3,
                  const float* __restrict__ v3,
                  int8_t* __restrict__ w1qp, float* __restrict__ ws1, float* __restrict__ bf1,
                  int8_t* __restrict__ w2qi, float* __restrict__ ws2, float* __restrict__ bf2,
                  int8_t* __restrict__ w3qp, float* __restrict__ ws3, float* __restrict__ bf3)
{
    int blk  = blockIdx.x;
    int lane = threadIdx.x;

    const float *w, *g, *bb, *mm, *vv;
    int oc, K, which;
    if (blk < CMID)            { which = 0; w = w1; g = g1; bb = b1; mm = m1; vv = v1; oc = blk;            K = CIN;  }
    else if (blk < 2 * CMID)   { which = 1; w = w2; g = g2; bb = b2; mm = m2; vv = v2; oc = blk - CMID;     K = 9;    }
    else                       { which = 2; w = w3; g = g3; bb = b3; mm = m3; vv = v3; oc = blk - 2 * CMID; K = CMID; }

    float scale = g[oc] / sqrtf(vv[oc] + EPSF);

    float mx = 0.f;
    for (int k = lane; k < K; k += 64)
        mx = fmaxf(mx, fabsf(w[oc * K + k] * scale));
    #pragma unroll
    for (int off = 1; off < 64; off <<= 1)
        mx = fmaxf(mx, __shfl_xor(mx, off));

    float s = mx / NBITF;

    for (int k = lane; k < K; k += 64) {
        float wf = w[oc * K + k] * scale;
        float q  = fminf(fmaxf(rintf(wf / s), -127.f), 127.f);
        if (which == 0)      w1qp[oc * 144 + k] = (int8_t)q;
        else if (which == 1) w2qi[oc * 12 + k]  = (int8_t)q;
        else                 w3qp[oc * 592 + k] = (int8_t)q;
    }
    if (which == 0 && lane < 12)   // zero K-pad 96..143 (dwords 24..35)
        ((u32*)(w1qp + oc * 144))[24 + lane] = 0u;
    if (lane == 0) {
        float bf = bb[oc] - mm[oc] * scale;
        if (which == 0)      { ws1[oc] = s; bf1[oc] = bf; }
        else if (which == 1) { ws2[oc] = s; bf2[oc] = bf; }
        else                 { ws3[oc] = s; bf3[oc] = bf; }
    }
}

// ---------------------------------------------------------------------------
// quant_x: fp32 x -> int8 levels, transposed to [b][px][144] with K-pad zeros.
// Block per (ptile 112 px, b). LDS register-transpose (v_perm), coalesced I/O.
// ---------------------------------------------------------------------------
__global__ __launch_bounds__(256)
void quant_x(const float* __restrict__ x, const float* __restrict__ r0,
             const int* __restrict__ cluster, int8_t* __restrict__ x8t)
{
    __shared__ u32 T[112 * 37];   // rows = px, 37-dw stride (148 B) to spread banks

    int tid = threadIdx.x, pt = blockIdx.x, b = blockIdx.y;
    float inv_s0 = NBITF / r0[cluster[0]];

    for (int i = tid; i < 112 * 13; i += 256) {      // zero dwords 24..36
        int row = i / 13, cpad = i - row * 13;
        T[row * 37 + 24 + cpad] = 0u;
    }
    // units: (icq 0..23, pq 0..27) -> 4 px x 4 ic, pq fastest (coalesced reads)
    for (int u = tid; u < 24 * 28; u += 256) {
        int pq = u % 28, icq = u / 28;
        int pxb = pt * 112 + pq * 4;
        int q[4][4];
        #pragma unroll
        for (int j = 0; j < 4; j++) {
            v4f xv = *(const v4f*)(x + ((size_t)b * CIN + icq * 4 + j) * P_ + pxb);
            #pragma unroll
            for (int i = 0; i < 4; i++)
                q[j][i] = (int)fminf(fmaxf(rintf(xv[i] * inv_s0), -127.f), 127.f);
        }
        #pragma unroll
        for (int i = 0; i < 4; i++) {
            u32 t0 = __builtin_amdgcn_perm((u32)q[1][i], (u32)q[0][i], 0x00000400u);
            u32 t1 = __builtin_amdgcn_perm((u32)q[3][i], (u32)q[2][i], 0x00000400u);
            T[(pq * 4 + i) * 37 + icq] = __builtin_amdgcn_perm(t1, t0, 0x05040100u);
        }
    }
    __syncthreads();
    u32* gdst = (u32*)x8t;
    for (int i = tid; i < 112 * 36; i += 256) {      // coalesced copy-out
        int row = i / 36, cc = i - row * 36;
        gdst[((size_t)b * P_ + pt * 112 + row) * 36 + cc] = T[row * 37 + cc];
    }
}

// ---------------------------------------------------------------------------
// conv12: fused 1x1 expansion (int8 MFMA) + ReLU6/quant + 3x3 depthwise +
// ReLU6/quant, emitting transposed y2qT. Block = 192 oc x 4 y1-rows (2 out
// rows). Grid (3 mt x 14 rt, 64 b). 4 waves m-split (48 oc each).
// ---------------------------------------------------------------------------
__global__ __launch_bounds__(256)
void conv12(const int8_t* __restrict__ x8t, const int8_t* __restrict__ w1qp,
            const float* __restrict__ ws1, const float* __restrict__ bf1,
            const int8_t* __restrict__ w2qi, const float* __restrict__ ws2,
            const float* __restrict__ bf2,
            const float* __restrict__ r0, const float* __restrict__ r1,
            const float* __restrict__ r2, const int* __restrict__ cluster,
            int8_t* __restrict__ y2qT)
{
    __shared__ int8_t AY[192 * 144];   // phase 1: A tile; phase 3: y2s (56*200)
    __shared__ int8_t y1s[192 * 132];  // per-ch 4 rows x 32 B (halo-framed)

    int tid = threadIdx.x;
    int b   = blockIdx.y;
    int mt  = blockIdx.x / 14, rt = blockIdx.x - mt * 14;
    int oc0 = mt * 192;
    int R0  = rt * 2;              // first output row
    int W0  = (R0 - 1) * 28;       // first y1-window px (may be -28)

    int   c      = cluster[0];
    float s0     = r0[c] / NBITF;
    float s1     = r1[c] / NBITF;
    float inv_s1 = NBITF / r1[c];
    float inv_s2 = NBITF / r2[c];
    float u1     = fminf(rintf(6.f * inv_s1), 127.f);
    float u2     = fminf(rintf(6.f * inv_s2), 127.f);

    // ---- stage A (192 x 144 B) ----
    {
        const v4i* gsrc = (const v4i*)(w1qp + (size_t)oc0 * 144);
        v4i* ldst = (v4i*)AY;
        for (int i = tid; i < 192 * 9; i += 256) ldst[i] = gsrc[i];
    }
    __syncthreads();

    int lane = tid & 63, wv = tid >> 6;
    int n = lane & 15, q4 = lane >> 4;

    // B row pointers (7 px-subtiles), clamped for halo rows
    const v4i* bp[7];
    #pragma unroll
    for (int j = 0; j < 7; j++) {
        int px = W0 + j * 16 + n;
        px = min(max(px, 0), P_ - 1);
        bp[j] = (const v4i*)(x8t + ((size_t)b * P_ + px) * 144) + q4;
    }

    v4i acc[3][7];
    #pragma unroll
    for (int i = 0; i < 3; i++)
        #pragma unroll
        for (int j = 0; j < 7; j++) acc[i][j] = (v4i){0, 0, 0, 0};

    const v4i* Af = (const v4i*)AY;
    #pragma unroll
    for (int ks = 0; ks < 2; ks++) {
        v4i bfr[7], afr[3];
        #pragma unroll
        for (int j = 0; j < 7; j++) bfr[j] = bp[j][ks * 4];
        #pragma unroll
        for (int i = 0; i < 3; i++)
            afr[i] = Af[(wv * 48 + i * 16 + n) * 9 + ks * 4 + q4];
        #pragma unroll
        for (int i = 0; i < 3; i++)
            #pragma unroll
            for (int j = 0; j < 7; j++)
                acc[i][j] = __builtin_amdgcn_mfma_i32_16x16x64_i8(afr[i], bfr[j], acc[i][j], 0, 0, 0);
    }

    // ---- epilogue 1: y1 = quant(relu6(acc*sc+bias)) -> LDS bytes ----
    float sA[3][4], bA[3][4];
    #pragma unroll
    for (int i = 0; i < 3; i++)
        #pragma unroll
        for (int r = 0; r < 4; r++) {
            int oc = oc0 + wv * 48 + i * 16 + q4 * 4 + r;
            sA[i][r] = s0 * ws1[oc] * inv_s1;
            bA[i][r] = bf1[oc] * inv_s1;
        }
    // halo frame zeros: bytes 0, 29..31 of each (ch,row)  [192*4 = 768 rows]
    for (int i = tid; i < 192 * 4; i += 256) {
        int ch = i >> 2, r = i & 3;
        int8_t* p = y1s + ch * 132 + r * 32;
        p[0] = 0; p[29] = 0; *(short*)(p + 30) = 0;
    }
    #pragma unroll
    for (int i = 0; i < 3; i++)
        #pragma unroll
        for (int j = 0; j < 7; j++) {
            int pxl = j * 16 + n;
            bool valid = (unsigned)(W0 + pxl) < (unsigned)P_;
            int rowl = pxl / 28, col = pxl - rowl * 28;
            int chl = wv * 48 + i * 16 + q4 * 4;
            #pragma unroll
            for (int r = 0; r < 4; r++) {
                float t = fmaf((float)acc[i][j][r], sA[i][r], bA[i][r]);
                t = fminf(fmaxf(rintf(t), 0.f), u1);
                int lvl = valid ? (int)t : 0;
                y1s[(chl + r) * 132 + rowl * 32 + 1 + col] = (int8_t)lvl;
            }
        }
    __syncthreads();

    // ---- depthwise 3x3 from LDS; write y2s (px-major) ----
    int8_t* y2s = AY;   // 56 px x 200 B (reuses A space; A dead after sync)
    for (int idx = tid; idx < 192 * 14; idx += 256) {
        int xq   = idx % 7;
        int t2   = idx / 7;
        int orow = t2 & 1;
        int chl  = t2 >> 1;
        int chg  = oc0 + chl;

        const u32* wd = (const u32*)(w2qi + chg * 12);
        u32 wr0 = wd[0], wr1 = wd[1], wr2 = wd[2];
        u32 pk0 = wr0 & 0x00ffffffu;
        u32 pk1 = __builtin_amdgcn_perm(wr1, wr0, 0x00050403u) & 0x00ffffffu;
        u32 pk2 = __builtin_amdgcn_perm(wr2, wr1, 0x00040302u) & 0x00ffffffu;

        const int8_t* base = y1s + chl * 132 + orow * 32;
        int a0 = 0, a1 = 0, a2 = 0, a3 = 0;
        #pragma unroll
        for (int dr = 0; dr < 3; dr++) {
            const u32* row = (const u32*)(base + dr * 32);
            u32 d0 = row[xq], d1 = row[xq + 1];
            u32 pk = (dr == 0) ? pk0 : (dr == 1) ? pk1 : pk2;
            a0 = dot3(d0, pk, a0);
            a1 = dot3(__builtin_amdgcn_alignbyte(d1, d0, 1), pk, a1);
            a2 = dot3(__builtin_amdgcn_alignbyte(d1, d0, 2), pk, a2);
            a3 = dot3(__builtin_amdgcn_alignbyte(d1, d0, 3), pk, a3);
        }
        float sc = s1 * ws2[chg] * inv_s2;
        float bb = bf2[chg] * inv_s2;
        int pxo = orow * 28 + xq * 4;
        int aa[4] = {a0, a1, a2, a3};
        #pragma unroll
        for (int i = 0; i < 4; i++) {
            float t = fmaf((float)aa[i], sc, bb);
            t = fminf(fmaxf(rintf(t), 0.f), u2);
            y2s[(pxo + i) * 200 + chl] = (int8_t)(int)t;
        }
    }
    __syncthreads();

    // ---- copy-out y2s -> y2qT (coalesced 48-dword runs) ----
    for (int i = tid; i < 56 * 48; i += 256) {
        int px = i / 48, cq = i - px * 48;
        u32 v = ((const u32*)(y2s + px * 200))[cq];
        ((u32*)y2qT)[((size_t)b * P_ + R0 * 28 + px) * 148 + (oc0 >> 2) + cq] = v;
    }
}

// ---------------------------------------------------------------------------
// conv3: 1x1 projection 576->96, A (w3) fully LDS-resident, B-fragments
// straight from y2qT global (k-contiguous). No per-chunk syncs.
// Fused residual + requant + s3. Grid (13, 64); wave = 16-px strip.
// ---------------------------------------------------------------------------
__global__ __launch_bounds__(256)
void conv3_kernel(const int8_t* __restrict__ y2qT, const int8_t* __restrict__ w3qp,
                  const float* __restrict__ ws3, const float* __restrict__ bf3,
                  const float* __restrict__ x, const float* __restrict__ r2,
                  const float* __restrict__ r3, const int* __restrict__ cluster,
                  float* __restrict__ out)
{
    __shared__ int8_t Ash[96 * 592];   // 56832 B

    int tid = threadIdx.x, b = blockIdx.y;
    int p0 = blockIdx.x * 64;

    int   c      = cluster[0];
    float s2     = r2[c] / NBITF;
    float s3     = r3[c] / NBITF;
    float inv_s3 = NBITF / r3[c];

    {
        const v4i* gs = (const v4i*)w3qp;
        v4i* ld = (v4i*)Ash;
        for (int i = tid; i < 96 * 37; i += 256) ld[i] = gs[i];
    }
    __syncthreads();

    int lane = tid & 63, wv = tid >> 6;
    int n = lane & 15, q4 = lane >> 4;
    int px  = p0 + wv * 16 + n;
    int pxc = min(px, P_ - 1);

    const v4i* brow = (const v4i*)(y2qT + ((size_t)b * P_ + pxc) * 592) + q4;
    const v4i* Af   = (const v4i*)Ash;

    v4i acc[6];
    #pragma unroll
    for (int i = 0; i < 6; i++) acc[i] = (v4i){0, 0, 0, 0};

    #pragma unroll
    for (int ks = 0; ks < 9; ks++) {
        v4i bfr = brow[ks * 4];
        #pragma unroll
        for (int i = 0; i < 6; i++) {
            v4i afr = Af[(i * 16 + n) * 37 + ks * 4 + q4];
            acc[i] = __builtin_amdgcn_mfma_i32_16x16x64_i8(afr, bfr, acc[i], 0, 0, 0);
        }
    }

    if (px < P_) {
        #pragma unroll
        for (int i = 0; i < 6; i++)
            #pragma unroll
            for (int r = 0; r < 4; r++) {
                int oc = i * 16 + q4 * 4 + r;
                size_t gi = ((size_t)b * COUT + oc) * P_ + px;
                float v  = (float)acc[i][r] * (s2 * ws3[oc]) + bf3[oc] + x[gi];
                float qv = fminf(fmaxf(rintf(v * inv_s3), -127.f), 127.f);
                out[gi] = qv * s3;
            }
    }
    if (blockIdx.x == 0 && blockIdx.y == 0 && tid == 0)
        out[NOUT] = s3;
}

// ---------------------------------------------------------------------------
extern "C" void kernel_launch(void* const* d_in, const int* in_sizes, int n_in,
                              void* d_out, int out_size, void* d_ws, size_t ws_size,
                              hipStream_t stream)
{
    const float* x  = (const float*)d_in[0];
    const float* w1 = (const float*)d_in[1];
    const float* g1 = (const float*)d_in[2];
    const float* b1 = (const float*)d_in[3];
    const float* m1 = (const float*)d_in[4];
    const float* v1 = (const float*)d_in[5];
    const float* w2 = (const float*)d_in[6];
    const float* g2 = (const float*)d_in[7];
    const float* b2 = (const float*)d_in[8];
    const float* m2 = (const float*)d_in[9];
    const float* v2 = (const float*)d_in[10];
    const float* w3 = (const float*)d_in[11];
    const float* g3 = (const float*)d_in[12];
    const float* b3 = (const float*)d_in[13];
    const float* m3 = (const float*)d_in[14];
    const float* v3 = (const float*)d_in[15];
    const float* r0 = (const float*)d_in[16];
    const float* r1 = (const float*)d_in[17];
    const float* r2 = (const float*)d_in[18];
    const float* r3 = (const float*)d_in[19];
    const int*   cl = (const int*)d_in[20];

    float* out = (float*)d_out;

    char*  ws  = (char*)d_ws;
    size_t off = 0;
    auto carve = [&](size_t bytes) {
        size_t cur = off;
        off = (off + bytes + 255) & ~(size_t)255;
        return (void*)(ws + cur);
    };
    int8_t* w1qp = (int8_t*)carve((size_t)CMID * 144);
    float*  ws1  = (float*)carve(CMID * 4);
    float*  bf1  = (float*)carve(CMID * 4);
    int8_t* w2qi = (int8_t*)carve((size_t)CMID * 12);
    float*  ws2  = (float*)carve(CMID * 4);
    float*  bf2  = (float*)carve(CMID * 4);
    int8_t* w3qp = (int8_t*)carve((size_t)COUT * 592);
    float*  ws3  = (float*)carve(COUT * 4);
    float*  bf3  = (float*)carve(COUT * 4);
    int8_t* x8t  = (int8_t*)carve((size_t)B_ * P_ * 144);   // 7.2 MB
    int8_t* y2qT = (int8_t*)carve((size_t)B_ * P_ * 592);   // 29.7 MB
    (void)ws_size; (void)in_sizes; (void)n_in; (void)out_size;

    prep_weights<<<dim3(2 * CMID + COUT), dim3(64), 0, stream>>>(
        w1, g1, b1, m1, v1, w2, g2, b2, m2, v2, w3, g3, b3, m3, v3,
        w1qp, ws1, bf1, w2qi, ws2, bf2, w3qp, ws3, bf3);

    quant_x<<<dim3(7, B_), dim3(256), 0, stream>>>(x, r0, cl, x8t);

    conv12<<<dim3(42, B_), dim3(256), 0, stream>>>(
        x8t, w1qp, ws1, bf1, w2qi, ws2, bf2, r0, r1, r2, cl, y2qT);

    conv3_kernel<<<dim3(13, B_), dim3(256), 0, stream>>>(
        y2qT, w3qp, ws3, bf3, x, r2, r3, cl, out);
}

// Round 4
// 191.042 us; speedup vs baseline: 2.8292x; 1.0068x over previous
//
#include <hip/hip_runtime.h>
#include <cstdint>
#include <cstddef>

typedef int   v4i __attribute__((ext_vector_type(4)));
typedef float v4f __attribute__((ext_vector_type(4)));
typedef unsigned int u32;

constexpr int B_   = 64;
constexpr int CIN  = 96;
constexpr int P_   = 784;     // 28*28
constexpr int CMID = 576;
constexpr int COUT = 96;
constexpr int NOUT = B_ * COUT * P_;
constexpr float NBITF = 127.0f;
constexpr float EPSF  = 1e-5f;

// D-layouts: dword D[b][pt][kdw][pxl] holds k-bytes 4*kdw..+3 of pixel pt*64+pxl.
//  x8t : kdw 0..23 = ic, 24..31 = zero (MFMA K-pad 96->128), 32..35 slack. 36/px.
//  y2qT: kdw 0..143 = ch 0..575. 144/px.
constexpr int XKD = 36;                 // x8t kdw stride
constexpr int YKD = 144;                // y2qT kdw stride
constexpr int XBD = 13 * XKD * 64;      // dwords per batch in x8t  (29952)
constexpr int YBD = 13 * YKD * 64;      // dwords per batch in y2qT (119808)

__device__ __forceinline__ int dot3(u32 a, u32 w, int acc) {
#if __has_builtin(__builtin_amdgcn_sdot4)
    return __builtin_amdgcn_sdot4((int)a, (int)w, acc, false);
#else
    return acc + (int)(signed char)(a)        * (int)(signed char)(w)
               + (int)(signed char)(a >> 8)   * (int)(signed char)(w >> 8)
               + (int)(signed char)(a >> 16)  * (int)(signed char)(w >> 16);
#endif
}

// 4x4 byte transpose: O[k] = [S0.byte_k, S1.byte_k, S2.byte_k, S3.byte_k]
__device__ __forceinline__ void tr4(u32 S0, u32 S1, u32 S2, u32 S3, u32 O[4]) {
    u32 u01 = __builtin_amdgcn_perm(S1, S0, 0x05010400u);  // [S0b0,S1b0,S0b1,S1b1]
    u32 u23 = __builtin_amdgcn_perm(S3, S2, 0x05010400u);
    u32 v01 = __builtin_amdgcn_perm(S1, S0, 0x07030602u);  // [S0b2,S1b2,S0b3,S1b3]
    u32 v23 = __builtin_amdgcn_perm(S3, S2, 0x07030602u);
    O[0] = __builtin_amdgcn_perm(u23, u01, 0x05040100u);
    O[1] = __builtin_amdgcn_perm(u23, u01, 0x07060302u);
    O[2] = __builtin_amdgcn_perm(v23, v01, 0x05040100u);
    O[3] = __builtin_amdgcn_perm(v23, v01, 0x07060302u);
}

// ---------------------------------------------------------------------------
// Weight prep: fold BN, per-oc symmetric quant -> int8 levels + scales.
// ---------------------------------------------------------------------------
__global__ __launch_bounds__(64)
void prep_weights(const float* __restrict__ w1, const float* __restrict__ g1,
                  const float* __restrict__ b1, const float* __restrict__ m1,
                  const float* __restrict__ v1,
                  const float* __restrict__ w2, const float* __restrict__ g2,
                  const float* __restrict__ b2, const float* __restrict__ m2,
                  const float* __restrict__ v2,
                  const float* __restrict__ w3, const float* __restrict__ g3,
                  const float* __restrict__ b3, const float* __restrict__ m3,
                  const float* __restrict__ v3,
                  int8_t* __restrict__ w1qp, float* __restrict__ ws1, float* __restrict__ bf1,
                  v4i* __restrict__ w2pk, float* __restrict__ ws2, float* __restrict__ bf2,
                  int8_t* __restrict__ w3qp, float* __restrict__ ws3, float* __restrict__ bf3)
{
    int blk  = blockIdx.x;
    int lane = threadIdx.x;

    const float *w, *g, *bb, *mm, *vv;
    int oc, K, which;
    if (blk < CMID)            { which = 0; w = w1; g = g1; bb = b1; mm = m1; vv = v1; oc = blk;            K = CIN;  }
    else if (blk < 2 * CMID)   { which = 1; w = w2; g = g2; bb = b2; mm = m2; vv = v2; oc = blk - CMID;     K = 9;    }
    else                       { which = 2; w = w3; g = g3; bb = b3; mm = m3; vv = v3; oc = blk - 2 * CMID; K = CMID; }

    float scale = g[oc] / sqrtf(vv[oc] + EPSF);

    float mx = 0.f;
    for (int k = lane; k < K; k += 64)
        mx = fmaxf(mx, fabsf(w[oc * K + k] * scale));
    #pragma unroll
    for (int off = 1; off < 64; off <<= 1)
        mx = fmaxf(mx, __shfl_xor(mx, off));

    float s = mx / NBITF;

    int myq = 0;
    for (int k = lane; k < K; k += 64) {
        float wf = w[oc * K + k] * scale;
        float q  = fminf(fmaxf(rintf(wf / s), -127.f), 127.f);
        if (which == 0)      w1qp[oc * 144 + k] = (int8_t)q;
        else if (which == 1) myq = (int)q;
        else                 w3qp[oc * 592 + k] = (int8_t)q;
    }
    if (which == 0 && lane < 12)   // zero K-pad dwords 24..35
        ((u32*)(w1qp + oc * 144))[24 + lane] = 0u;
    if (which == 1) {
        u32 qq[9];
        #pragma unroll
        for (int t = 0; t < 9; t++) qq[t] = (u32)__shfl(myq, t, 64) & 0xffu;
        if (lane == 0) {
            v4i pk;
            pk[0] = (int)(qq[0] | (qq[1] << 8) | (qq[2] << 16));
            pk[1] = (int)(qq[3] | (qq[4] << 8) | (qq[5] << 16));
            pk[2] = (int)(qq[6] | (qq[7] << 8) | (qq[8] << 16));
            pk[3] = 0;
            w2pk[oc] = pk;
        }
    }
    if (lane == 0) {
        float bf = bb[oc] - mm[oc] * scale;
        if (which == 0)      { ws1[oc] = s; bf1[oc] = bf; }
        else if (which == 1) { ws2[oc] = s; bf2[oc] = bf; }
        else                 { ws3[oc] = s; bf3[oc] = bf; }
    }
}

// ---------------------------------------------------------------------------
// quant_x: fp32 x -> int8 levels in D-layout x8t (k-pad dwords zeroed).
// Block = (112 px, b). LDS 4x4 perm transpose; coalesced global I/O.
// ---------------------------------------------------------------------------
__global__ __launch_bounds__(256)
void quant_x(const float* __restrict__ x, const float* __restrict__ r0,
             const int* __restrict__ cluster, u32* __restrict__ x8t)
{
    __shared__ u32 T[112 * 37];   // [px][icq], stride 37 dw

    int tid = threadIdx.x, pt0 = blockIdx.x, b = blockIdx.y;
    float inv_s0 = NBITF / r0[cluster[0]];

    for (int i = tid; i < 112 * 12; i += 256) {      // zero k-pad dwords 24..35
        int row = i / 12, cpad = i - row * 12;
        T[row * 37 + 24 + cpad] = 0u;
    }
    // (icq 0..23, pq 0..27): 4 px x 4 ic; pq fastest -> coalesced v4f reads
    for (int u = tid; u < 24 * 28; u += 256) {
        int pq = u % 28, icq = u / 28;
        int pxb = pt0 * 112 + pq * 4;
        int q[4][4];
        #pragma unroll
        for (int j = 0; j < 4; j++) {
            v4f xv = *(const v4f*)(x + ((size_t)b * CIN + icq * 4 + j) * P_ + pxb);
            #pragma unroll
            for (int i = 0; i < 4; i++)
                q[j][i] = (int)fminf(fmaxf(rintf(xv[i] * inv_s0), -127.f), 127.f);
        }
        #pragma unroll
        for (int i = 0; i < 4; i++) {
            u32 t0 = __builtin_amdgcn_perm((u32)q[1][i], (u32)q[0][i], 0x00000400u);
            u32 t1 = __builtin_amdgcn_perm((u32)q[3][i], (u32)q[2][i], 0x00000400u);
            T[(pq * 4 + i) * 37 + icq] = __builtin_amdgcn_perm(t1, t0, 0x05040100u);
        }
    }
    __syncthreads();
    u32* gb = x8t + (size_t)b * XBD;
    for (int i = tid; i < XKD * 112; i += 256) {     // px-fast -> coalesced
        int icq = i / 112, pxo = i - icq * 112;
        int px = pt0 * 112 + pxo;
        gb[(((px >> 6) * XKD) + icq) * 64 + (px & 63)] = T[pxo * 37 + icq];
    }
}

// ---------------------------------------------------------------------------
// conv12: 1x1 expansion (int8 MFMA, K pad 128) + ReLU6 quant + 3x3 depthwise
// + ReLU6 quant -> y2qT D-layout. Block: 192 oc x 2 out rows (4 y1 rows).
// Grid (3 mt x 14 rt, 64). All-dword LDS; two perm transposes.
// ---------------------------------------------------------------------------
__global__ __launch_bounds__(256)
void conv12(const u32* __restrict__ x8t, const int8_t* __restrict__ w1qp,
            const float* __restrict__ ws1, const float* __restrict__ bf1,
            const v4i* __restrict__ w2pk, const float* __restrict__ ws2,
            const float* __restrict__ bf2,
            const float* __restrict__ r0, const float* __restrict__ r1,
            const float* __restrict__ r2, const int* __restrict__ cluster,
            u32* __restrict__ y2qT)
{
    __shared__ u32 AY[6912];   // ph1: A [192oc][36dw]; ph3+: y1t [192ch][33dw]
    __shared__ u32 PB[5488];   // ph2: y1p [112px][49dw]; ph4: y2s2 [192ch][15dw]

    int tid = threadIdx.x;
    int b   = blockIdx.y;
    int mt  = blockIdx.x / 14, rt = blockIdx.x - mt * 14;
    int oc0 = mt * 192;
    int R0  = rt * 2;
    int W0  = (R0 - 1) * 28;

    int   c      = cluster[0];
    float s0     = r0[c] / NBITF;
    float s1     = r1[c] / NBITF;
    float inv_s1 = NBITF / r1[c];
    float inv_s2 = NBITF / r2[c];
    float u1     = fminf(rintf(6.f * inv_s1), 127.f);
    float u2     = fminf(rintf(6.f * inv_s2), 127.f);

    // stage A (192 x 144 B, v4i coalesced)
    {
        const v4i* gs = (const v4i*)(w1qp + (size_t)oc0 * 144);
        v4i* ld = (v4i*)AY;
        for (int i = tid; i < 192 * 9; i += 256) ld[i] = gs[i];
    }
    __syncthreads();

    int lane = tid & 63, wv = tid >> 6;
    int n = lane & 15, q4 = lane >> 4;

    const u32* xb = x8t + (size_t)b * XBD;
    int pbase[7];
    #pragma unroll
    for (int j = 0; j < 7; j++) {
        int px = W0 + j * 16 + n;
        px = min(max(px, 0), P_ - 1);
        pbase[j] = ((px >> 6) * XKD) * 64 + (px & 63);
    }

    v4i acc[3][7];
    #pragma unroll
    for (int i = 0; i < 3; i++)
        #pragma unroll
        for (int j = 0; j < 7; j++) acc[i][j] = (v4i){0, 0, 0, 0};

    const v4i* Af = (const v4i*)AY;
    #pragma unroll
    for (int ks = 0; ks < 2; ks++) {
        int k0 = ks * 16 + q4 * 4;
        v4i bfr[7], afr[3];
        #pragma unroll
        for (int j = 0; j < 7; j++) {
            u32 d0 = xb[pbase[j] + (k0 + 0) * 64];
            u32 d1 = xb[pbase[j] + (k0 + 1) * 64];
            u32 d2 = xb[pbase[j] + (k0 + 2) * 64];
            u32 d3 = xb[pbase[j] + (k0 + 3) * 64];
            bfr[j] = (v4i){(int)d0, (int)d1, (int)d2, (int)d3};
        }
        #pragma unroll
        for (int i = 0; i < 3; i++)
            afr[i] = Af[(wv * 48 + i * 16 + n) * 9 + ks * 4 + q4];
        #pragma unroll
        for (int i = 0; i < 3; i++)
            #pragma unroll
            for (int j = 0; j < 7; j++)
                acc[i][j] = __builtin_amdgcn_mfma_i32_16x16x64_i8(afr[i], bfr[j], acc[i][j], 0, 0, 0);
    }

    // epilogue 1: quant(relu6(acc)) -> packed ch-quad dwords into y1p[px][chq]
    float sA[3][4], bA[3][4];
    #pragma unroll
    for (int i = 0; i < 3; i++)
        #pragma unroll
        for (int r = 0; r < 4; r++) {
            int oc = oc0 + wv * 48 + i * 16 + q4 * 4 + r;
            sA[i][r] = s0 * ws1[oc] * inv_s1;
            bA[i][r] = bf1[oc] * inv_s1;
        }
    #pragma unroll
    for (int i = 0; i < 3; i++) {
        int chq = wv * 12 + i * 4 + q4;
        #pragma unroll
        for (int j = 0; j < 7; j++) {
            int pxl = j * 16 + n;
            bool valid = (unsigned)(W0 + pxl) < (unsigned)P_;
            u32 pk = 0;
            #pragma unroll
            for (int r = 0; r < 4; r++) {
                float t = fmaf((float)acc[i][j][r], sA[i][r], bA[i][r]);
                t = fminf(fmaxf(rintf(t), 0.f), u1);
                pk |= ((u32)(int)t) << (8 * r);
            }
            PB[pxl * 49 + chq] = valid ? pk : 0u;
        }
    }
    __syncthreads();

    // transpose y1p[px][chq] -> y1t[ch][row][8dw], byte k of dw c = px 4c-1+k
    for (int u = tid; u < 1536; u += 256) {
        int cc = u & 7, rowl = (u >> 3) & 3, chq = u >> 5;
        u32 S[4];
        #pragma unroll
        for (int k = 0; k < 4; k++) {
            int col = 4 * cc - 1 + k;
            S[k] = ((unsigned)col < 28u) ? PB[(rowl * 28 + col) * 49 + chq] : 0u;
        }
        u32 O[4];
        tr4(S[0], S[1], S[2], S[3], O);
        int bse = chq * 132 + rowl * 8 + cc;   // (4*chq)*33
        #pragma unroll
        for (int r = 0; r < 4; r++) AY[bse + r * 33] = O[r];
    }
    __syncthreads();

    // depthwise 3x3 via sdot4; output px-packed dwords y2s2[ch][opx]
    for (int u = tid; u < 2688; u += 256) {
        int xq = u % 7;
        int t2 = u / 7;
        int orow = t2 & 1;
        int chl  = t2 >> 1;
        int chg  = oc0 + chl;

        v4i wpk = w2pk[chg];
        int base = chl * 33 + orow * 8;
        int a0 = 0, a1 = 0, a2 = 0, a3 = 0;
        #pragma unroll
        for (int dr = 0; dr < 3; dr++) {
            u32 d0 = AY[base + dr * 8 + xq];
            u32 d1 = AY[base + dr * 8 + xq + 1];
            u32 pk = (u32)((dr == 0) ? wpk[0] : (dr == 1) ? wpk[1] : wpk[2]);
            a0 = dot3(d0, pk, a0);
            a1 = dot3(__builtin_amdgcn_alignbyte(d1, d0, 1), pk, a1);
            a2 = dot3(__builtin_amdgcn_alignbyte(d1, d0, 2), pk, a2);
            a3 = dot3(__builtin_amdgcn_alignbyte(d1, d0, 3), pk, a3);
        }
        float sc = s1 * ws2[chg] * inv_s2;
        float bb = bf2[chg] * inv_s2;
        int aa[4] = {a0, a1, a2, a3};
        u32 pk2 = 0;
        #pragma unroll
        for (int i = 0; i < 4; i++) {
            float t = fmaf((float)aa[i], sc, bb);
            t = fminf(fmaxf(rintf(t), 0.f), u2);
            pk2 |= ((u32)(int)t) << (8 * i);
        }
        PB[chl * 15 + orow * 7 + xq] = pk2;
    }
    __syncthreads();

    // copy-out: transpose px-packed -> ch-packed, write y2qT D-layout
    u32* yb = y2qT + (size_t)b * YBD;
    int kdw0 = mt * 48;
    for (int u = tid; u < 672; u += 256) {
        int pxq = u % 14, chq = u / 14;
        int orow = pxq / 7, xq = pxq - orow * 7;
        u32 S[4];
        #pragma unroll
        for (int r = 0; r < 4; r++) S[r] = PB[(chq * 4 + r) * 15 + pxq];
        u32 O[4];
        tr4(S[0], S[1], S[2], S[3], O);
        #pragma unroll
        for (int k = 0; k < 4; k++) {
            int gpx = (R0 + orow) * 28 + xq * 4 + k;
            yb[((gpx >> 6) * YKD + kdw0 + chq) * 64 + (gpx & 63)] = O[k];
        }
    }
}

// ---------------------------------------------------------------------------
// conv3: 1x1 projection 576->96. A fully LDS-resident; B coalesced dword
// loads from y2qT D-layout. Fused residual + requant + s3. Grid (13, 64).
// ---------------------------------------------------------------------------
__global__ __launch_bounds__(256)
void conv3_kernel(const u32* __restrict__ y2qT, const int8_t* __restrict__ w3qp,
                  const float* __restrict__ ws3, const float* __restrict__ bf3,
                  const float* __restrict__ x, const float* __restrict__ r2,
                  const float* __restrict__ r3, const int* __restrict__ cluster,
                  float* __restrict__ out)
{
    __shared__ u32 Ash[96 * 148];   // [oc][148 dw] = 592 B rows (16B-aligned)

    int tid = threadIdx.x, b = blockIdx.y, pt = blockIdx.x;

    int   c      = cluster[0];
    float s2     = r2[c] / NBITF;
    float s3     = r3[c] / NBITF;
    float inv_s3 = NBITF / r3[c];

    {
        const v4i* gs = (const v4i*)w3qp;
        v4i* ld = (v4i*)Ash;
        for (int i = tid; i < 96 * 37; i += 256) ld[i] = gs[i];
    }
    __syncthreads();

    int lane = tid & 63, wv = tid >> 6;
    int n = lane & 15, q4 = lane >> 4;
    int pxl = wv * 16 + n;

    const u32* yb = y2qT + (size_t)b * YBD + (size_t)pt * (YKD * 64) + pxl;
    const v4i* Af = (const v4i*)Ash;

    v4i acc[6];
    #pragma unroll
    for (int i = 0; i < 6; i++) acc[i] = (v4i){0, 0, 0, 0};

    #pragma unroll
    for (int ks = 0; ks < 9; ks++) {
        int k0 = ks * 16 + q4 * 4;
        u32 d0 = yb[(k0 + 0) * 64];
        u32 d1 = yb[(k0 + 1) * 64];
        u32 d2 = yb[(k0 + 2) * 64];
        u32 d3 = yb[(k0 + 3) * 64];
        v4i bfr = (v4i){(int)d0, (int)d1, (int)d2, (int)d3};
        #pragma unroll
        for (int i = 0; i < 6; i++) {
            v4i afr = Af[(i * 16 + n) * 37 + ks * 4 + q4];
            acc[i] = __builtin_amdgcn_mfma_i32_16x16x64_i8(afr, bfr, acc[i], 0, 0, 0);
        }
    }

    int px = pt * 64 + pxl;
    if (px < P_) {
        #pragma unroll
        for (int i = 0; i < 6; i++)
            #pragma unroll
            for (int r = 0; r < 4; r++) {
                int oc = i * 16 + q4 * 4 + r;
                size_t gi = ((size_t)b * COUT + oc) * P_ + px;
                float v  = (float)acc[i][r] * (s2 * ws3[oc]) + bf3[oc] + x[gi];
                float qv = fminf(fmaxf(rintf(v * inv_s3), -127.f), 127.f);
                out[gi] = qv * s3;
            }
    }
    if (pt == 0 && b == 0 && tid == 0)
        out[NOUT] = s3;
}

// ---------------------------------------------------------------------------
extern "C" void kernel_launch(void* const* d_in, const int* in_sizes, int n_in,
                              void* d_out, int out_size, void* d_ws, size_t ws_size,
                              hipStream_t stream)
{
    const float* x  = (const float*)d_in[0];
    const float* w1 = (const float*)d_in[1];
    const float* g1 = (const float*)d_in[2];
    const float* b1 = (const float*)d_in[3];
    const float* m1 = (const float*)d_in[4];
    const float* v1 = (const float*)d_in[5];
    const float* w2 = (const float*)d_in[6];
    const float* g2 = (const float*)d_in[7];
    const float* b2 = (const float*)d_in[8];
    const float* m2 = (const float*)d_in[9];
    const float* v2 = (const float*)d_in[10];
    const float* w3 = (const float*)d_in[11];
    const float* g3 = (const float*)d_in[12];
    const float* b3 = (const float*)d_in[13];
    const float* m3 = (const float*)d_in[14];
    const float* v3 = (const float*)d_in[15];
    const float* r0 = (const float*)d_in[16];
    const float* r1 = (const float*)d_in[17];
    const float* r2 = (const float*)d_in[18];
    const float* r3 = (const float*)d_in[19];
    const int*   cl = (const int*)d_in[20];

    float* out = (float*)d_out;

    char*  ws  = (char*)d_ws;
    size_t off = 0;
    auto carve = [&](size_t bytes) {
        size_t cur = off;
        off = (off + bytes + 255) & ~(size_t)255;
        return (void*)(ws + cur);
    };
    int8_t* w1qp = (int8_t*)carve((size_t)CMID * 144);
    float*  ws1  = (float*)carve(CMID * 4);
    float*  bf1  = (float*)carve(CMID * 4);
    v4i*    w2pk = (v4i*)carve((size_t)CMID * 16);
    float*  ws2  = (float*)carve(CMID * 4);
    float*  bf2  = (float*)carve(CMID * 4);
    int8_t* w3qp = (int8_t*)carve((size_t)COUT * 592);
    float*  ws3  = (float*)carve(COUT * 4);
    float*  bf3  = (float*)carve(COUT * 4);
    u32*    x8t  = (u32*)carve((size_t)B_ * XBD * 4);   // 7.7 MB
    u32*    y2qT = (u32*)carve((size_t)B_ * YBD * 4);   // 30.7 MB
    (void)ws_size; (void)in_sizes; (void)n_in; (void)out_size;

    prep_weights<<<dim3(2 * CMID + COUT), dim3(64), 0, stream>>>(
        w1, g1, b1, m1, v1, w2, g2, b2, m2, v2, w3, g3, b3, m3, v3,
        w1qp, ws1, bf1, w2pk, ws2, bf2, w3qp, ws3, bf3);

    quant_x<<<dim3(7, B_), dim3(256), 0, stream>>>(x, r0, cl, x8t);

    conv12<<<dim3(42, B_), dim3(256), 0, stream>>>(
        x8t, w1qp, ws1, bf1, w2pk, ws2, bf2, r0, r1, r2, cl, y2qT);

    conv3_kernel<<<dim3(13, B_), dim3(256), 0, stream>>>(
        y2qT, w3qp, ws3, bf3, x, r2, r3, cl, out);
}

// Round 5
// 187.744 us; speedup vs baseline: 2.8789x; 1.0176x over previous
//
#include <hip/hip_runtime.h>
#include <cstdint>
#include <cstddef>

typedef int   v4i __attribute__((ext_vector_type(4)));
typedef float v4f __attribute__((ext_vector_type(4)));
typedef unsigned int u32;

constexpr int B_   = 64;
constexpr int CIN  = 96;
constexpr int P_   = 784;     // 28*28
constexpr int CMID = 576;
constexpr int COUT = 96;
constexpr int NOUT = B_ * COUT * P_;
constexpr float NBITF = 127.0f;
constexpr float EPSF  = 1e-5f;
constexpr float MAGICF = 12582912.0f;    // 1.5 * 2^23
constexpr int   BIASI  = 0x4B400000;     // float bits of MAGICF

// x8t D-layout: dword [b][pt13][kdw][pxl64] = k-bytes 4kdw..+3 of px pt*64+pxl
//   kdw 0..23 = ic 0..95, 24..31 = zero (K pad 96->128), 32..35 slack
constexpr int XKD = 36;
constexpr int XBD = 13 * XKD * 64;   // dwords per batch (29952)
// y1px / y2px: plain [b][ch 576][784 bytes] (196 dwords per ch row)

__device__ __forceinline__ int dot3(u32 a, u32 w, int acc) {
#if __has_builtin(__builtin_amdgcn_sdot4)
    return __builtin_amdgcn_sdot4((int)a, (int)w, acc, false);
#else
    return acc + (int)(signed char)(a)        * (int)(signed char)(w)
               + (int)(signed char)(a >> 8)   * (int)(signed char)(w >> 8)
               + (int)(signed char)(a >> 16)  * (int)(signed char)(w >> 16);
#endif
}

__device__ __forceinline__ void tr4(u32 S0, u32 S1, u32 S2, u32 S3, u32 O[4]) {
    u32 u01 = __builtin_amdgcn_perm(S1, S0, 0x05010400u);
    u32 u23 = __builtin_amdgcn_perm(S3, S2, 0x05010400u);
    u32 v01 = __builtin_amdgcn_perm(S1, S0, 0x07030602u);
    u32 v23 = __builtin_amdgcn_perm(S3, S2, 0x07030602u);
    O[0] = __builtin_amdgcn_perm(u23, u01, 0x05040100u);
    O[1] = __builtin_amdgcn_perm(u23, u01, 0x07060302u);
    O[2] = __builtin_amdgcn_perm(v23, v01, 0x05040100u);
    O[3] = __builtin_amdgcn_perm(v23, v01, 0x07060302u);
}

// pack low byte of 4 clamped magic-floats into one dword
__device__ __forceinline__ u32 pack4(u32 t0, u32 t1, u32 t2, u32 t3) {
    u32 p01 = __builtin_amdgcn_perm(t1, t0, 0x05010400u);
    u32 p23 = __builtin_amdgcn_perm(t3, t2, 0x05010400u);
    return __builtin_amdgcn_perm(p23, p01, 0x05040100u);
}

// ---------------------------------------------------------------------------
// Weight prep: fold BN, per-oc symmetric quant -> int8 levels + scales.
// ---------------------------------------------------------------------------
__global__ __launch_bounds__(64)
void prep_weights(const float* __restrict__ w1, const float* __restrict__ g1,
                  const float* __restrict__ b1, const float* __restrict__ m1,
                  const float* __restrict__ v1,
                  const float* __restrict__ w2, const float* __restrict__ g2,
                  const float* __restrict__ b2, const float* __restrict__ m2,
                  const float* __restrict__ v2,
                  const float* __restrict__ w3, const float* __restrict__ g3,
                  const float* __restrict__ b3, const float* __restrict__ m3,
                  const float* __restrict__ v3,
                  int8_t* __restrict__ w1qp, float* __restrict__ ws1, float* __restrict__ bf1,
                  v4i* __restrict__ w2pk, float* __restrict__ ws2, float* __restrict__ bf2,
                  int8_t* __restrict__ w3qp, float* __restrict__ ws3, float* __restrict__ bf3)
{
    int blk  = blockIdx.x;
    int lane = threadIdx.x;

    const float *w, *g, *bb, *mm, *vv;
    int oc, K, which;
    if (blk < CMID)            { which = 0; w = w1; g = g1; bb = b1; mm = m1; vv = v1; oc = blk;            K = CIN;  }
    else if (blk < 2 * CMID)   { which = 1; w = w2; g = g2; bb = b2; mm = m2; vv = v2; oc = blk - CMID;     K = 9;    }
    else                       { which = 2; w = w3; g = g3; bb = b3; mm = m3; vv = v3; oc = blk - 2 * CMID; K = CMID; }

    float scale = g[oc] / sqrtf(vv[oc] + EPSF);

    float mx = 0.f;
    for (int k = lane; k < K; k += 64)
        mx = fmaxf(mx, fabsf(w[oc * K + k] * scale));
    #pragma unroll
    for (int off = 1; off < 64; off <<= 1)
        mx = fmaxf(mx, __shfl_xor(mx, off));

    float s = mx / NBITF;

    int myq = 0;
    for (int k = lane; k < K; k += 64) {
        float wf = w[oc * K + k] * scale;
        float q  = fminf(fmaxf(rintf(wf / s), -127.f), 127.f);
        if (which == 0)      w1qp[oc * 144 + k] = (int8_t)q;
        else if (which == 1) myq = (int)q;
        else                 w3qp[oc * 592 + k] = (int8_t)q;
    }
    if (which == 0 && lane < 12)
        ((u32*)(w1qp + oc * 144))[24 + lane] = 0u;
    if (which == 1) {
        u32 qq[9];
        #pragma unroll
        for (int t = 0; t < 9; t++) qq[t] = (u32)__shfl(myq, t, 64) & 0xffu;
        if (lane == 0) {
            v4i pk;
            pk[0] = (int)(qq[0] | (qq[1] << 8) | (qq[2] << 16));
            pk[1] = (int)(qq[3] | (qq[4] << 8) | (qq[5] << 16));
            pk[2] = (int)(qq[6] | (qq[7] << 8) | (qq[8] << 16));
            pk[3] = 0;
            w2pk[oc] = pk;
        }
    }
    if (lane == 0) {
        float bf = bb[oc] - mm[oc] * scale;
        if (which == 0)      { ws1[oc] = s; bf1[oc] = bf; }
        else if (which == 1) { ws2[oc] = s; bf2[oc] = bf; }
        else                 { ws3[oc] = s; bf3[oc] = bf; }
    }
}

// ---------------------------------------------------------------------------
// quant_x: fp32 x -> int8 levels in x8t D-layout (k-pad zeroed).
// ---------------------------------------------------------------------------
__global__ __launch_bounds__(256)
void quant_x(const float* __restrict__ x, const float* __restrict__ r0,
             const int* __restrict__ cluster, u32* __restrict__ x8t)
{
    __shared__ u32 T[112 * 37];

    int tid = threadIdx.x, pt0 = blockIdx.x, b = blockIdx.y;
    float inv_s0 = NBITF / r0[cluster[0]];

    for (int i = tid; i < 112 * 12; i += 256) {
        int row = i / 12, cpad = i - row * 12;
        T[row * 37 + 24 + cpad] = 0u;
    }
    for (int u = tid; u < 24 * 28; u += 256) {
        int pq = u % 28, icq = u / 28;
        int pxb = pt0 * 112 + pq * 4;
        int q[4][4];
        #pragma unroll
        for (int j = 0; j < 4; j++) {
            v4f xv = *(const v4f*)(x + ((size_t)b * CIN + icq * 4 + j) * P_ + pxb);
            #pragma unroll
            for (int i = 0; i < 4; i++)
                q[j][i] = (int)fminf(fmaxf(rintf(xv[i] * inv_s0), -127.f), 127.f);
        }
        #pragma unroll
        for (int i = 0; i < 4; i++) {
            u32 t0 = __builtin_amdgcn_perm((u32)q[1][i], (u32)q[0][i], 0x00000400u);
            u32 t1 = __builtin_amdgcn_perm((u32)q[3][i], (u32)q[2][i], 0x00000400u);
            T[(pq * 4 + i) * 37 + icq] = __builtin_amdgcn_perm(t1, t0, 0x05040100u);
        }
    }
    __syncthreads();
    u32* gb = x8t + (size_t)b * XBD;
    for (int i = tid; i < XKD * 112; i += 256) {
        int icq = i / 112, pxo = i - icq * 112;
        int px = pt0 * 112 + pxo;
        gb[(((px >> 6) * XKD) + icq) * 64 + (px & 63)] = T[pxo * 37 + icq];
    }
}

// ---------------------------------------------------------------------------
// conv1s: 1x1 expansion, OPERAND-SWAPPED MFMA (A = x px-major, B = w1) so the
// accumulator holds 4 consecutive px of one oc -> px-packed dword stores.
// No LDS, no barriers. Block 256 = 4 waves; wave = 48 oc x 64 px.
// Grid (3 mt x 13 pt, 64 b).
// ---------------------------------------------------------------------------
__global__ __launch_bounds__(256)
void conv1s(const u32* __restrict__ x8t, const int8_t* __restrict__ w1qp,
            const float* __restrict__ ws1, const float* __restrict__ bf1,
            const float* __restrict__ r0, const float* __restrict__ r1,
            const int* __restrict__ cluster, u32* __restrict__ y1px)
{
    int tid = threadIdx.x, b = blockIdx.y;
    int mt = blockIdx.x % 3, pt = blockIdx.x / 3;
    int p0 = pt * 64;
    int lane = tid & 63, wv = tid >> 6;
    int n = lane & 15, q4 = lane >> 4;
    int ocw = mt * 192 + wv * 48;

    int   c      = cluster[0];
    float s0     = r0[c] / NBITF;
    float inv_s1 = NBITF / r1[c];
    int   u1i    = (int)fminf(rintf(6.f * inv_s1), 127.f);

    const u32* xb = x8t + (size_t)b * XBD;
    int abase[4];
    #pragma unroll
    for (int jm = 0; jm < 4; jm++) {
        int px = p0 + 16 * jm + n;
        px = min(px, P_ - 1);
        abase[jm] = ((px >> 6) * XKD) * 64 + (px & 63);
    }

    v4i acc[3][4];
    #pragma unroll
    for (int jn = 0; jn < 3; jn++)
        #pragma unroll
        for (int jm = 0; jm < 4; jm++) acc[jn][jm] = (v4i){0, 0, 0, 0};

    const v4i* w4 = (const v4i*)w1qp;   // 9 v4i per oc
    #pragma unroll
    for (int ks = 0; ks < 2; ks++) {
        v4i bfr[3], afr[4];
        #pragma unroll
        for (int jn = 0; jn < 3; jn++) {
            int oc = ocw + 16 * jn + n;
            bfr[jn] = w4[oc * 9 + ks * 4 + q4];
        }
        #pragma unroll
        for (int jm = 0; jm < 4; jm++) {
            int kb = (16 * ks + 4 * q4) * 64;
            u32 d0 = xb[abase[jm] + kb];
            u32 d1 = xb[abase[jm] + kb + 64];
            u32 d2 = xb[abase[jm] + kb + 128];
            u32 d3 = xb[abase[jm] + kb + 192];
            afr[jm] = (v4i){(int)d0, (int)d1, (int)d2, (int)d3};
        }
        #pragma unroll
        for (int jn = 0; jn < 3; jn++)
            #pragma unroll
            for (int jm = 0; jm < 4; jm++)
                acc[jn][jm] = __builtin_amdgcn_mfma_i32_16x16x64_i8(afr[jm], bfr[jn], acc[jn][jm], 0, 0, 0);
    }

    // epilogue: scale/bias/ReLU6/quant via magic rounding; px-packed stores
    #pragma unroll
    for (int jn = 0; jn < 3; jn++) {
        int   oc  = ocw + 16 * jn + n;
        float scv = s0 * ws1[oc] * inv_s1;
        float bbv = bf1[oc] * inv_s1;
        size_t rowbase = (size_t)(b * CMID + oc) * 196 + (p0 >> 2);
        #pragma unroll
        for (int jm = 0; jm < 4; jm++) {
            int quad = p0 + 16 * jm + 4 * q4;
            u32 t[4];
            #pragma unroll
            for (int r = 0; r < 4; r++) {
                float f = fmaf((float)acc[jn][jm][r], scv, bbv) + MAGICF;
                int v = __float_as_int(f);
                t[r] = (u32)min(max(v, BIASI), BIASI + u1i);
            }
            if (quad < P_)
                y1px[rowbase + 4 * jm + q4] = pack4(t[0], t[1], t[2], t[3]);
        }
    }
}

// ---------------------------------------------------------------------------
// conv2s: 3x3 depthwise, px-packed in/out, no LDS. Thread = (b, ch, row):
// 21 dword loads, alignbyte+sdot4 core, magic-round epilogue.
// ---------------------------------------------------------------------------
__global__ __launch_bounds__(256)
void conv2s(const u32* __restrict__ y1px, const v4i* __restrict__ w2pk,
            const float* __restrict__ ws2, const float* __restrict__ bf2,
            const float* __restrict__ r1, const float* __restrict__ r2,
            const int* __restrict__ cluster, u32* __restrict__ y2px)
{
    int gid = blockIdx.x * 256 + threadIdx.x;   // == 64*576*28 exactly
    int r  = gid % 28;
    int t  = gid / 28;
    int ch = t % CMID;
    int b  = t / CMID;

    int   c      = cluster[0];
    float s1     = r1[c] / NBITF;
    float inv_s2 = NBITF / r2[c];
    int   u2i    = (int)fminf(rintf(6.f * inv_s2), 127.f);

    const u32* base = y1px + (size_t)(b * CMID + ch) * 196;
    u32 R[3][7];
    #pragma unroll
    for (int dr = 0; dr < 3; dr++) {
        int rr = r + dr - 1;
        bool ok = (unsigned)rr < 28u;
        #pragma unroll
        for (int j = 0; j < 7; j++)
            R[dr][j] = ok ? base[rr * 7 + j] : 0u;
    }

    v4i wpk = w2pk[ch];
    u32 pk0 = (u32)wpk[0], pk1 = (u32)wpk[1], pk2 = (u32)wpk[2];
    float scv = s1 * ws2[ch] * inv_s2;
    float bbv = bf2[ch] * inv_s2;

    u32* orow = y2px + (size_t)(b * CMID + ch) * 196 + r * 7;
    #pragma unroll
    for (int j = 0; j < 7; j++) {
        int a0 = 0, a1 = 0, a2 = 0, a3 = 0;
        #pragma unroll
        for (int dr = 0; dr < 3; dr++) {
            u32 D   = R[dr][j];
            u32 Dm1 = (j > 0) ? R[dr][j - 1] : 0u;
            u32 Dp1 = (j < 6) ? R[dr][j + 1] : 0u;
            u32 pk  = (dr == 0) ? pk0 : (dr == 1) ? pk1 : pk2;
            a0 = dot3(__builtin_amdgcn_alignbyte(D, Dm1, 3), pk, a0);
            a1 = dot3(D, pk, a1);
            a2 = dot3(__builtin_amdgcn_alignbyte(Dp1, D, 1), pk, a2);
            a3 = dot3(__builtin_amdgcn_alignbyte(Dp1, D, 2), pk, a3);
        }
        int aa[4] = {a0, a1, a2, a3};
        u32 tq[4];
        #pragma unroll
        for (int i = 0; i < 4; i++) {
            float f = fmaf((float)aa[i], scv, bbv) + MAGICF;
            int v = __float_as_int(f);
            tq[i] = (u32)min(max(v, BIASI), BIASI + u2i);
        }
        orow[j] = pack4(tq[0], tq[1], tq[2], tq[3]);
    }
}

// ---------------------------------------------------------------------------
// conv3s: 1x1 projection 576->96. One LDS bounce transposes y2 px-packed ->
// ch-packed (tr4); A (w3) frags straight from L2; fused residual + requant.
// Block 256 = 4 waves x 16 px; grid (13 pt, 64 b). LDS 38.6 KB.
// ---------------------------------------------------------------------------
__global__ __launch_bounds__(256)
void conv3s(const u32* __restrict__ y2px, const int8_t* __restrict__ w3qp,
            const float* __restrict__ ws3, const float* __restrict__ bf3,
            const float* __restrict__ x, const float* __restrict__ r2,
            const float* __restrict__ r3, const int* __restrict__ cluster,
            float* __restrict__ out)
{
    __shared__ u32 Bsh[144 * 67];   // [kdw ch-quad][67: 64 px + 3 pad]

    int tid = threadIdx.x, b = blockIdx.y, pt = blockIdx.x;
    int p0d = pt * 16;              // dword col base within 196-dw ch rows

    int   c      = cluster[0];
    float s2     = r2[c] / NBITF;
    float s3     = r3[c] / NBITF;
    float inv_s3 = NBITF / r3[c];

    // stage + transpose: y2px [ch][px-dwords] -> Bsh [chq][pxl]
    for (int u = tid; u < 2304; u += 256) {
        int pxq = u & 15, chq = u >> 4;
        u32 S[4];
        #pragma unroll
        for (int r = 0; r < 4; r++) {
            int col = min(p0d + pxq, 195);
            S[r] = y2px[(size_t)(b * CMID + 4 * chq + r) * 196 + col];
        }
        u32 O[4];
        tr4(S[0], S[1], S[2], S[3], O);
        #pragma unroll
        for (int k = 0; k < 4; k++)
            Bsh[chq * 67 + 4 * pxq + k] = O[k];
    }
    __syncthreads();

    int lane = tid & 63, wv = tid >> 6;
    int n = lane & 15, q4 = lane >> 4;
    int pxl = wv * 16 + n;

    v4i acc[6];
    #pragma unroll
    for (int i = 0; i < 6; i++) acc[i] = (v4i){0, 0, 0, 0};

    #pragma unroll
    for (int ks = 0; ks < 9; ks++) {
        int kr = 16 * ks + 4 * q4;
        u32 b0 = Bsh[(kr + 0) * 67 + pxl];
        u32 b1 = Bsh[(kr + 1) * 67 + pxl];
        u32 b2 = Bsh[(kr + 2) * 67 + pxl];
        u32 b3 = Bsh[(kr + 3) * 67 + pxl];
        v4i bfr = (v4i){(int)b0, (int)b1, (int)b2, (int)b3};
        #pragma unroll
        for (int i = 0; i < 6; i++) {
            v4i afr = *(const v4i*)(w3qp + (size_t)(i * 16 + n) * 592 + ks * 64 + q4 * 16);
            acc[i] = __builtin_amdgcn_mfma_i32_16x16x64_i8(afr, bfr, acc[i], 0, 0, 0);
        }
    }

    int px = pt * 64 + pxl;
    if (px < P_) {
        #pragma unroll
        for (int i = 0; i < 6; i++) {
            #pragma unroll
            for (int r = 0; r < 4; r++) {
                int oc = i * 16 + q4 * 4 + r;
                size_t gi = (size_t)(b * COUT + oc) * P_ + px;
                float v  = (float)acc[i][r] * (s2 * ws3[oc]) + bf3[oc] + x[gi];
                float f  = fmaf(v, inv_s3, MAGICF);
                int lvl  = min(max(__float_as_int(f) - BIASI, -127), 127);
                out[gi]  = (float)lvl * s3;
            }
        }
    }
    if (pt == 0 && b == 0 && tid == 0)
        out[NOUT] = s3;
}

// ---------------------------------------------------------------------------
extern "C" void kernel_launch(void* const* d_in, const int* in_sizes, int n_in,
                              void* d_out, int out_size, void* d_ws, size_t ws_size,
                              hipStream_t stream)
{
    const float* x  = (const float*)d_in[0];
    const float* w1 = (const float*)d_in[1];
    const float* g1 = (const float*)d_in[2];
    const float* b1 = (const float*)d_in[3];
    const float* m1 = (const float*)d_in[4];
    const float* v1 = (const float*)d_in[5];
    const float* w2 = (const float*)d_in[6];
    const float* g2 = (const float*)d_in[7];
    const float* b2 = (const float*)d_in[8];
    const float* m2 = (const float*)d_in[9];
    const float* v2 = (const float*)d_in[10];
    const float* w3 = (const float*)d_in[11];
    const float* g3 = (const float*)d_in[12];
    const float* b3 = (const float*)d_in[13];
    const float* m3 = (const float*)d_in[14];
    const float* v3 = (const float*)d_in[15];
    const float* r0 = (const float*)d_in[16];
    const float* r1 = (const float*)d_in[17];
    const float* r2 = (const float*)d_in[18];
    const float* r3 = (const float*)d_in[19];
    const int*   cl = (const int*)d_in[20];

    float* out = (float*)d_out;

    char*  ws  = (char*)d_ws;
    size_t off = 0;
    auto carve = [&](size_t bytes) {
        size_t cur = off;
        off = (off + bytes + 255) & ~(size_t)255;
        return (void*)(ws + cur);
    };
    int8_t* w1qp = (int8_t*)carve((size_t)CMID * 144);
    float*  ws1  = (float*)carve(CMID * 4);
    float*  bf1  = (float*)carve(CMID * 4);
    v4i*    w2pk = (v4i*)carve((size_t)CMID * 16);
    float*  ws2  = (float*)carve(CMID * 4);
    float*  bf2  = (float*)carve(CMID * 4);
    int8_t* w3qp = (int8_t*)carve((size_t)COUT * 592);
    float*  ws3  = (float*)carve(COUT * 4);
    float*  bf3  = (float*)carve(COUT * 4);
    u32*    y1px = (u32*)carve((size_t)B_ * CMID * 196 * 4);  // 28.9 MB
    u32*    y2px = (u32*)carve((size_t)B_ * CMID * 196 * 4);  // 28.9 MB
    u32*    x8t  = y2px;  // alias: x8t (7.7 MB) dead before conv2s writes y2px
    (void)ws_size; (void)in_sizes; (void)n_in; (void)out_size;

    prep_weights<<<dim3(2 * CMID + COUT), dim3(64), 0, stream>>>(
        w1, g1, b1, m1, v1, w2, g2, b2, m2, v2, w3, g3, b3, m3, v3,
        w1qp, ws1, bf1, w2pk, ws2, bf2, w3qp, ws3, bf3);

    quant_x<<<dim3(7, B_), dim3(256), 0, stream>>>(x, r0, cl, x8t);

    conv1s<<<dim3(39, B_), dim3(256), 0, stream>>>(
        x8t, w1qp, ws1, bf1, r0, r1, cl, y1px);

    conv2s<<<dim3((B_ * CMID * 28) / 256), dim3(256), 0, stream>>>(
        y1px, w2pk, ws2, bf2, r1, r2, cl, y2px);

    conv3s<<<dim3(13, B_), dim3(256), 0, stream>>>(
        y2px, w3qp, ws3, bf3, x, r2, r3, cl, out);
}